// Round 1
// baseline (403.636 us; speedup 1.0000x reference)
//
#include <hip/hip_runtime.h>
#include <hip/hip_bf16.h>

typedef __attribute__((ext_vector_type(8))) short bf16x8;
typedef __attribute__((ext_vector_type(4))) float f32x4;

#define MFMA16(a, b, c) __builtin_amdgcn_mfma_f32_16x16x32_bf16(a, b, c, 0, 0, 0)

static __device__ __forceinline__ unsigned short f2bf(float f) {
  union { __hip_bfloat16 h; unsigned short u; } cv;
  cv.h = __float2bfloat16(f);
  return cv.u;
}

// ---------------- small prep kernels ----------------

__global__ void f32_to_bf16_k(const float* __restrict__ in, __hip_bfloat16* __restrict__ out, int n) {
  int i = blockIdx.x * 256 + threadIdx.x;
  if (i < n) out[i] = __float2bfloat16(in[i]);
}

__global__ void bn_st_k(const float* __restrict__ g, const float* __restrict__ b,
                        const float* __restrict__ m, const float* __restrict__ v,
                        float* __restrict__ s, float* __restrict__ t, int n) {
  int i = blockIdx.x * 256 + threadIdx.x;
  if (i < n) {
    float sv = g[i] * rsqrtf(v[i] + 1e-5f);
    s[i] = sv;
    t[i] = b[i] - m[i] * sv;
  }
}

// x (B,512,4096) fp32 -> xT (B,4096,512) bf16
__global__ __launch_bounds__(256) void transpose_k(const float* __restrict__ x,
                                                   __hip_bfloat16* __restrict__ xT) {
  __shared__ float tile[64][65];
  const int n0 = blockIdx.x * 64, c0 = blockIdx.y * 64, b = blockIdx.z;
  const int tx = threadIdx.x, ty = threadIdx.y;
  const float* xp = x + ((size_t)(b * 512 + c0) * 4096) + n0;
#pragma unroll
  for (int i = 0; i < 16; ++i) {
    int c = ty + 4 * i;
    tile[c][tx] = xp[(size_t)c * 4096 + tx];
  }
  __syncthreads();
  __hip_bfloat16* op = xT + ((size_t)(b * 4096 + n0) * 512) + c0;
#pragma unroll
  for (int i = 0; i < 16; ++i) {
    int nl = ty + 4 * i;
    op[(size_t)nl * 512 + tx] = __float2bfloat16(tile[tx][nl]);
  }
}

// ---------------- NT GEMM: C(MxN) = A(MxK) . B(NxK)^T ----------------
// EPI 0: bf16 store; 1: BN+ReLU by col, bf16; 2: BN+ReLU by row, fp32
template <int EPI>
__global__ __launch_bounds__(256) void gemm_nt_k(
    const __hip_bfloat16* __restrict__ A, long sA,
    const __hip_bfloat16* __restrict__ B, long sB,
    void* __restrict__ Cp, long sC,
    int lda, int ldb, int ldc, int K,
    const float* __restrict__ s, const float* __restrict__ t) {
  __shared__ short As[128][72];
  __shared__ short Bs[128][72];
  const int tid = threadIdx.x;
  const int w = tid >> 6, l = tid & 63, g = l >> 4, ln = l & 15;
  const int wr = w >> 1, wc = w & 1;
  const int rb = blockIdx.x * 128, cb = blockIdx.y * 128;
  const __hip_bfloat16* Ab = A + (size_t)blockIdx.z * sA;
  const __hip_bfloat16* Bb = B + (size_t)blockIdx.z * sB;

  f32x4 acc[4][4];
#pragma unroll
  for (int i = 0; i < 4; ++i)
#pragma unroll
    for (int j = 0; j < 4; ++j) acc[i][j] = (f32x4){0.f, 0.f, 0.f, 0.f};

  const int r0 = tid >> 3;        // 0..31
  const int c8 = (tid & 7) * 8;   // 0..56

  for (int k0 = 0; k0 < K; k0 += 64) {
#pragma unroll
    for (int i = 0; i < 4; ++i) {
      const int r = r0 + 32 * i;
      *(uint4*)&As[r][c8] = *(const uint4*)(Ab + (size_t)(rb + r) * lda + (k0 + c8));
      *(uint4*)&Bs[r][c8] = *(const uint4*)(Bb + (size_t)(cb + r) * ldb + (k0 + c8));
    }
    __syncthreads();
#pragma unroll
    for (int kk = 0; kk < 2; ++kk) {
      bf16x8 av[4], bv[4];
#pragma unroll
      for (int i = 0; i < 4; ++i) av[i] = *(const bf16x8*)&As[64 * wr + 16 * i + ln][32 * kk + 8 * g];
#pragma unroll
      for (int i = 0; i < 4; ++i) bv[i] = *(const bf16x8*)&Bs[64 * wc + 16 * i + ln][32 * kk + 8 * g];
#pragma unroll
      for (int mi = 0; mi < 4; ++mi)
#pragma unroll
        for (int ni = 0; ni < 4; ++ni)
          acc[mi][ni] = MFMA16(av[mi], bv[ni], acc[mi][ni]);
    }
    __syncthreads();
  }

  const int row0 = rb + 64 * wr + 4 * g;
  const int col0 = cb + 64 * wc + ln;

  if (EPI == 2) {
    float* C = (float*)Cp + (size_t)blockIdx.z * sC;
#pragma unroll
    for (int mi = 0; mi < 4; ++mi) {
#pragma unroll
      for (int r = 0; r < 4; ++r) {
        const int R = row0 + 16 * mi + r;
        const float sr = s[R], tr = t[R];
#pragma unroll
        for (int ni = 0; ni < 4; ++ni) {
          float v = fmaf(acc[mi][ni][r], sr, tr);
          C[(size_t)R * ldc + (col0 + 16 * ni)] = v > 0.f ? v : 0.f;
        }
      }
    }
  } else {
    __hip_bfloat16* C = (__hip_bfloat16*)Cp + (size_t)blockIdx.z * sC;
    float sc[4], tc[4];
    if (EPI == 1) {
#pragma unroll
      for (int ni = 0; ni < 4; ++ni) { sc[ni] = s[col0 + 16 * ni]; tc[ni] = t[col0 + 16 * ni]; }
    }
#pragma unroll
    for (int mi = 0; mi < 4; ++mi) {
#pragma unroll
      for (int ni = 0; ni < 4; ++ni) {
#pragma unroll
        for (int r = 0; r < 4; ++r) {
          float v = acc[mi][ni][r];
          if (EPI == 1) { v = fmaf(v, sc[ni], tc[ni]); v = v > 0.f ? v : 0.f; }
          C[(size_t)(row0 + 16 * mi + r) * ldc + (col0 + 16 * ni)] = __float2bfloat16(v);
        }
      }
    }
  }
}

// ---------------- flash attention ----------------
// Q,K: (B, 4096, 256) bf16 (row = spatial n, contiguous channels)
// V:   (B, 256, 4096) bf16 (row = channel, contiguous spatial)
// O:   (B, 4096, 256) bf16
// grid 256 blocks: batch = bid&7 (XCD-aligned), qblock = bid>>3 (128 rows)
__global__ __launch_bounds__(512) void flash_k(
    const __hip_bfloat16* __restrict__ Q,
    const __hip_bfloat16* __restrict__ Kt,
    const __hip_bfloat16* __restrict__ V,
    __hip_bfloat16* __restrict__ O) {
  __shared__ short Ks[32][264];    // 32 keys x 256 ch (pad 8)
  __shared__ short Vs[256][40];    // 256 ch x 32 keys (pad 8)
  __shared__ short Ps[8][16][40];  // per-wave P: 16 q-rows x 32 keys (pad 8)

  const int tid = threadIdx.x;
  const int w = tid >> 6;
  const int l = tid & 63;
  const int g = l >> 4;
  const int ln = l & 15;
  const int bid = blockIdx.x;
  const int batch = bid & 7;
  const int qb = (bid >> 3) << 7;
  const size_t bo = (size_t)batch * (4096 * 256);
  const float CE = 0.09016844005556021f;  // log2(e) / sqrt(256)

  // Q fragments (B-operand layout): lane ln = q-row, k = 32*kk + 8*g + j
  bf16x8 qf[8];
  {
    const __hip_bfloat16* qp = Q + bo + (size_t)(qb + 16 * w + ln) * 256 + 8 * g;
#pragma unroll
    for (int kk = 0; kk < 8; ++kk) qf[kk] = *(const bf16x8*)(qp + 32 * kk);
  }

  f32x4 acc[16];
#pragma unroll
  for (int ci = 0; ci < 16; ++ci) acc[ci] = (f32x4){0.f, 0.f, 0.f, 0.f};
  float m_run = -1e30f, l_run = 0.f;

  const int kr = tid >> 4, kc = (tid & 15) * 8;   // K staging
  const int vr = tid >> 1, vc = (tid & 1) * 16;   // V staging
  const __hip_bfloat16* Kb = Kt + bo;
  const __hip_bfloat16* Vb = V + bo;

  for (int m0 = 0; m0 < 4096; m0 += 32) {
    // stage K tile (32x256) and V tile (256x32)
    *(uint4*)&Ks[kr][kc] = *(const uint4*)(Kb + (size_t)(m0 + kr) * 256 + kc);
    *(uint4*)&Ks[kr][kc + 128] = *(const uint4*)(Kb + (size_t)(m0 + kr) * 256 + kc + 128);
    *(uint4*)&Vs[vr][vc] = *(const uint4*)(Vb + (size_t)vr * 4096 + m0 + vc);
    *(uint4*)&Vs[vr][vc + 8] = *(const uint4*)(Vb + (size_t)vr * 4096 + m0 + vc + 8);
    __syncthreads();

    // S^T = K . Q^T : lane ln = q-row, rows = key index (16*mi + 4*g + r)
    f32x4 sf0 = (f32x4){0.f, 0.f, 0.f, 0.f};
    f32x4 sf1 = (f32x4){0.f, 0.f, 0.f, 0.f};
#pragma unroll
    for (int kk = 0; kk < 8; ++kk) {
      bf16x8 a0 = *(const bf16x8*)&Ks[ln][32 * kk + 8 * g];
      bf16x8 a1 = *(const bf16x8*)&Ks[16 + ln][32 * kk + 8 * g];
      sf0 = MFMA16(a0, qf[kk], sf0);
      sf1 = MFMA16(a1, qf[kk], sf1);
    }

    float sv[8] = {sf0[0], sf0[1], sf0[2], sf0[3], sf1[0], sf1[1], sf1[2], sf1[3]};
    float mmax = sv[0];
#pragma unroll
    for (int j = 1; j < 8; ++j) mmax = fmaxf(mmax, sv[j]);
    mmax = fmaxf(mmax, __shfl_xor(mmax, 16));
    mmax = fmaxf(mmax, __shfl_xor(mmax, 32));

    if (!__all((mmax - m_run) * CE <= 8.0f)) {  // defer-max (T13)
      float m_new = fmaxf(m_run, mmax);
      float alpha = exp2f((m_run - m_new) * CE);
      l_run *= alpha;
#pragma unroll
      for (int ci = 0; ci < 16; ++ci) acc[ci] *= alpha;
      m_run = m_new;
    }
    float p[8], psum = 0.f;
#pragma unroll
    for (int j = 0; j < 8; ++j) {
      p[j] = exp2f((sv[j] - m_run) * CE);
      psum += p[j];
    }
    psum += __shfl_xor(psum, 16);
    psum += __shfl_xor(psum, 32);
    l_run += psum;

    // pack P (bf16) into per-wave LDS: Ps[w][q-row][key]
#pragma unroll
    for (int mi = 0; mi < 2; ++mi) {
      uint2 pk;
      pk.x = (unsigned int)f2bf(p[4 * mi + 0]) | ((unsigned int)f2bf(p[4 * mi + 1]) << 16);
      pk.y = (unsigned int)f2bf(p[4 * mi + 2]) | ((unsigned int)f2bf(p[4 * mi + 3]) << 16);
      *(uint2*)&Ps[w][ln][16 * mi + 4 * g] = pk;
    }
    asm volatile("s_waitcnt lgkmcnt(0)" ::: "memory");
    __builtin_amdgcn_sched_barrier(0);

    // PV: ctx[q-row][cv] += P . V^T
    bf16x8 pa = *(const bf16x8*)&Ps[w][ln][8 * g];
#pragma unroll
    for (int ci = 0; ci < 16; ++ci) {
      bf16x8 vfr = *(const bf16x8*)&Vs[16 * ci + ln][8 * g];
      acc[ci] = MFMA16(pa, vfr, acc[ci]);
    }
    __syncthreads();
  }

  // epilogue: redistribute row-sums, normalize, store
  float linv[4];
#pragma unroll
  for (int r = 0; r < 4; ++r) linv[r] = 1.0f / __shfl(l_run, 4 * g + r);

  __hip_bfloat16* Ob = O + bo;
#pragma unroll
  for (int ci = 0; ci < 16; ++ci) {
#pragma unroll
    for (int r = 0; r < 4; ++r) {
      float val = acc[ci][r] * linv[r];
      Ob[(size_t)(qb + 16 * w + 4 * g + r) * 256 + 16 * ci + ln] = __float2bfloat16(val);
    }
  }
}

// ---------------- host launcher ----------------

extern "C" void kernel_launch(void* const* d_in, const int* in_sizes, int n_in,
                              void* d_out, int out_size, void* d_ws, size_t ws_size,
                              hipStream_t stream) {
  const float* x   = (const float*)d_in[0];
  const float* kW1 = (const float*)d_in[1];
  const float* kG1 = (const float*)d_in[2];
  const float* kB1 = (const float*)d_in[3];
  const float* kM1 = (const float*)d_in[4];
  const float* kV1 = (const float*)d_in[5];
  const float* kW2 = (const float*)d_in[6];
  const float* kG2 = (const float*)d_in[7];
  const float* kB2 = (const float*)d_in[8];
  const float* kM2 = (const float*)d_in[9];
  const float* kV2 = (const float*)d_in[10];
  const float* qW1 = (const float*)d_in[11];
  const float* qG1 = (const float*)d_in[12];
  const float* qB1 = (const float*)d_in[13];
  const float* qM1 = (const float*)d_in[14];
  const float* qV1 = (const float*)d_in[15];
  const float* qW2 = (const float*)d_in[16];
  const float* qG2 = (const float*)d_in[17];
  const float* qB2 = (const float*)d_in[18];
  const float* qM2 = (const float*)d_in[19];
  const float* qV2 = (const float*)d_in[20];
  const float* vW  = (const float*)d_in[21];
  const float* wW  = (const float*)d_in[22];
  const float* wG  = (const float*)d_in[23];
  const float* wB  = (const float*)d_in[24];
  const float* wM  = (const float*)d_in[25];
  const float* wV  = (const float*)d_in[26];

  char* ws = (char*)d_ws;
  __hip_bfloat16* bQW1 = (__hip_bfloat16*)(ws + 0);
  __hip_bfloat16* bKW1 = (__hip_bfloat16*)(ws + 262144);
  __hip_bfloat16* bQW2 = (__hip_bfloat16*)(ws + 524288);
  __hip_bfloat16* bKW2 = (__hip_bfloat16*)(ws + 655360);
  __hip_bfloat16* bVW  = (__hip_bfloat16*)(ws + 786432);
  __hip_bfloat16* bWW  = (__hip_bfloat16*)(ws + 1048576);
  float* sQ1 = (float*)(ws + 1310720);
  float* tQ1 = (float*)(ws + 1311744);
  float* sQ2 = (float*)(ws + 1312768);
  float* tQ2 = (float*)(ws + 1313792);
  float* sK1 = (float*)(ws + 1314816);
  float* tK1 = (float*)(ws + 1315840);
  float* sK2 = (float*)(ws + 1316864);
  float* tK2 = (float*)(ws + 1317888);
  float* sWo = (float*)(ws + 1318912);
  float* tWo = (float*)(ws + 1320960);
  __hip_bfloat16* xT   = (__hip_bfloat16*)(ws + 2097152);    // 32 MB
  __hip_bfloat16* bufA = (__hip_bfloat16*)(ws + 35651584);   // 16 MB (q1 / k1 / ctx)
  __hip_bfloat16* q2b  = (__hip_bfloat16*)(ws + 52428800);   // 16 MB
  __hip_bfloat16* k2b  = (__hip_bfloat16*)(ws + 69206016);   // 16 MB
  __hip_bfloat16* vB   = (__hip_bfloat16*)(ws + 85983232);   // 16 MB

  // weight conversion + BN folding
  f32_to_bf16_k<<<512, 256, 0, stream>>>(qW1, bQW1, 131072);
  f32_to_bf16_k<<<512, 256, 0, stream>>>(kW1, bKW1, 131072);
  f32_to_bf16_k<<<256, 256, 0, stream>>>(qW2, bQW2, 65536);
  f32_to_bf16_k<<<256, 256, 0, stream>>>(kW2, bKW2, 65536);
  f32_to_bf16_k<<<512, 256, 0, stream>>>(vW, bVW, 131072);
  f32_to_bf16_k<<<512, 256, 0, stream>>>(wW, bWW, 131072);
  bn_st_k<<<1, 256, 0, stream>>>(qG1, qB1, qM1, qV1, sQ1, tQ1, 256);
  bn_st_k<<<1, 256, 0, stream>>>(qG2, qB2, qM2, qV2, sQ2, tQ2, 256);
  bn_st_k<<<1, 256, 0, stream>>>(kG1, kB1, kM1, kV1, sK1, tK1, 256);
  bn_st_k<<<1, 256, 0, stream>>>(kG2, kB2, kM2, kV2, sK2, tK2, 256);
  bn_st_k<<<2, 256, 0, stream>>>(wG, wB, wM, wV, sWo, tWo, 512);

  // x -> xT (bf16, channel-contiguous)
  transpose_k<<<dim3(64, 8, 8), dim3(64, 4), 0, stream>>>(x, xT);

  // q1 = CBR(xT . qW1^T)  (4096 x 256, per batch)
  gemm_nt_k<1><<<dim3(32, 2, 8), 256, 0, stream>>>(xT, 2097152L, bQW1, 0L, bufA, 1048576L,
                                                   512, 512, 256, 512, sQ1, tQ1);
  // q2 = CBR(q1 . qW2^T)
  gemm_nt_k<1><<<dim3(32, 2, 8), 256, 0, stream>>>(bufA, 1048576L, bQW2, 0L, q2b, 1048576L,
                                                   256, 256, 256, 256, sQ2, tQ2);
  // k1
  gemm_nt_k<1><<<dim3(32, 2, 8), 256, 0, stream>>>(xT, 2097152L, bKW1, 0L, bufA, 1048576L,
                                                   512, 512, 256, 512, sK1, tK1);
  // k2
  gemm_nt_k<1><<<dim3(32, 2, 8), 256, 0, stream>>>(bufA, 1048576L, bKW2, 0L, k2b, 1048576L,
                                                   256, 256, 256, 256, sK2, tK2);
  // v = vW . x  -> (256 x 4096, per batch)
  gemm_nt_k<0><<<dim3(2, 32, 8), 256, 0, stream>>>(bVW, 0L, xT, 2097152L, vB, 1048576L,
                                                   512, 512, 4096, 512, nullptr, nullptr);
  // flash attention: ctx -> bufA (k1 is dead)
  flash_k<<<256, 512, 0, stream>>>(q2b, k2b, vB, bufA);
  // out = CBR_row(wW . ctx^T) -> d_out (fp32)
  gemm_nt_k<2><<<dim3(4, 32, 8), 256, 0, stream>>>(bWW, 0L, bufA, 1048576L, d_out, 2097152L,
                                                   256, 256, 4096, 256, sWo, tWo);
}

// Round 2
// 297.438 us; speedup vs baseline: 1.3570x; 1.3570x over previous
//
#include <hip/hip_runtime.h>
#include <hip/hip_bf16.h>

typedef __attribute__((ext_vector_type(8))) short bf16x8;
typedef __attribute__((ext_vector_type(4))) float f32x4;

#define MFMA16(a, b, c) __builtin_amdgcn_mfma_f32_16x16x32_bf16(a, b, c, 0, 0, 0)

static __device__ __forceinline__ unsigned short f2bf(float f) {
  union { __hip_bfloat16 h; unsigned short u; } cv;
  cv.h = __float2bfloat16(f);
  return cv.u;
}

static __device__ __forceinline__ void gload16(const void* gptr, void* lptr) {
  __builtin_amdgcn_global_load_lds(
      (const __attribute__((address_space(1))) void*)gptr,
      (__attribute__((address_space(3))) void*)lptr, 16, 0, 0);
}

// ---------------- fused prep kernels ----------------

// packs 6 weight arrays (fp32) into contiguous bf16 at dst
__global__ void conv_w_k(const float* __restrict__ qW1, const float* __restrict__ kW1,
                         const float* __restrict__ qW2, const float* __restrict__ kW2,
                         const float* __restrict__ vW, const float* __restrict__ wW,
                         __hip_bfloat16* __restrict__ dst) {
  int i = blockIdx.x * 256 + threadIdx.x;  // 0..655359
  const float* src; int off;
  if (i < 131072)      { src = qW1; off = i; }
  else if (i < 262144) { src = kW1; off = i - 131072; }
  else if (i < 327680) { src = qW2; off = i - 262144; }
  else if (i < 393216) { src = kW2; off = i - 327680; }
  else if (i < 524288) { src = vW;  off = i - 393216; }
  else                 { src = wW;  off = i - 524288; }
  dst[i] = __float2bfloat16(src[off]);
}

// 5 BN param sets -> s,t pairs at base (layout: q1,q2,k1,k2 @256 each, w @512)
__global__ void bn_all_k(const float* __restrict__ qG1, const float* __restrict__ qB1, const float* __restrict__ qM1, const float* __restrict__ qV1,
                         const float* __restrict__ qG2, const float* __restrict__ qB2, const float* __restrict__ qM2, const float* __restrict__ qV2,
                         const float* __restrict__ kG1, const float* __restrict__ kB1, const float* __restrict__ kM1, const float* __restrict__ kV1,
                         const float* __restrict__ kG2, const float* __restrict__ kB2, const float* __restrict__ kM2, const float* __restrict__ kV2,
                         const float* __restrict__ wG, const float* __restrict__ wB, const float* __restrict__ wM, const float* __restrict__ wV,
                         float* __restrict__ base) {
  int bidx = blockIdx.x, tid = threadIdx.x;
  const float *g, *b, *m, *v; float *s, *t; int i;
  if (bidx == 0)      { g = qG1; b = qB1; m = qM1; v = qV1; s = base;        t = base + 256;  i = tid; }
  else if (bidx == 1) { g = qG2; b = qB2; m = qM2; v = qV2; s = base + 512;  t = base + 768;  i = tid; }
  else if (bidx == 2) { g = kG1; b = kB1; m = kM1; v = kV1; s = base + 1024; t = base + 1280; i = tid; }
  else if (bidx == 3) { g = kG2; b = kB2; m = kM2; v = kV2; s = base + 1536; t = base + 1792; i = tid; }
  else                { g = wG;  b = wB;  m = wM;  v = wV;  s = base + 2048; t = base + 2560; i = (bidx - 4) * 256 + tid; }
  float sv = g[i] * rsqrtf(v[i] + 1e-5f);
  s[i] = sv;
  t[i] = b[i] - m[i] * sv;
}

// x (B,512,4096) fp32 -> xT (B,4096,512) bf16
__global__ __launch_bounds__(256) void transpose_k(const float* __restrict__ x,
                                                   __hip_bfloat16* __restrict__ xT) {
  __shared__ float tile[64][65];
  const int n0 = blockIdx.x * 64, c0 = blockIdx.y * 64, b = blockIdx.z;
  const int tx = threadIdx.x, ty = threadIdx.y;
  const float* xp = x + ((size_t)(b * 512 + c0) * 4096) + n0;
#pragma unroll
  for (int i = 0; i < 16; ++i) {
    int c = ty + 4 * i;
    tile[c][tx] = xp[(size_t)c * 4096 + tx];
  }
  __syncthreads();
  __hip_bfloat16* op = xT + ((size_t)(b * 4096 + n0) * 512) + c0;
#pragma unroll
  for (int i = 0; i < 16; ++i) {
    int nl = ty + 4 * i;
    op[(size_t)nl * 512 + tx] = __float2bfloat16(tile[tx][nl]);
  }
}

// ---------------- NT GEMM: C(MxN) = A(MxK) . B(NxK)^T ----------------
template <int EPI>
__global__ __launch_bounds__(256) void gemm_nt_k(
    const __hip_bfloat16* __restrict__ A, long sA,
    const __hip_bfloat16* __restrict__ B, long sB,
    void* __restrict__ Cp, long sC,
    int lda, int ldb, int ldc, int K,
    const float* __restrict__ s, const float* __restrict__ t) {
  __shared__ short As[128][72];
  __shared__ short Bs[128][72];
  const int tid = threadIdx.x;
  const int w = tid >> 6, l = tid & 63, g = l >> 4, ln = l & 15;
  const int wr = w >> 1, wc = w & 1;
  const int rb = blockIdx.x * 128, cb = blockIdx.y * 128;
  const __hip_bfloat16* Ab = A + (size_t)blockIdx.z * sA;
  const __hip_bfloat16* Bb = B + (size_t)blockIdx.z * sB;

  f32x4 acc[4][4];
#pragma unroll
  for (int i = 0; i < 4; ++i)
#pragma unroll
    for (int j = 0; j < 4; ++j) acc[i][j] = (f32x4){0.f, 0.f, 0.f, 0.f};

  const int r0 = tid >> 3;
  const int c8 = (tid & 7) * 8;

  for (int k0 = 0; k0 < K; k0 += 64) {
#pragma unroll
    for (int i = 0; i < 4; ++i) {
      const int r = r0 + 32 * i;
      *(uint4*)&As[r][c8] = *(const uint4*)(Ab + (size_t)(rb + r) * lda + (k0 + c8));
      *(uint4*)&Bs[r][c8] = *(const uint4*)(Bb + (size_t)(cb + r) * ldb + (k0 + c8));
    }
    __syncthreads();
#pragma unroll
    for (int kk = 0; kk < 2; ++kk) {
      bf16x8 av[4], bv[4];
#pragma unroll
      for (int i = 0; i < 4; ++i) av[i] = *(const bf16x8*)&As[64 * wr + 16 * i + ln][32 * kk + 8 * g];
#pragma unroll
      for (int i = 0; i < 4; ++i) bv[i] = *(const bf16x8*)&Bs[64 * wc + 16 * i + ln][32 * kk + 8 * g];
#pragma unroll
      for (int mi = 0; mi < 4; ++mi)
#pragma unroll
        for (int ni = 0; ni < 4; ++ni)
          acc[mi][ni] = MFMA16(av[mi], bv[ni], acc[mi][ni]);
    }
    __syncthreads();
  }

  const int row0 = rb + 64 * wr + 4 * g;
  const int col0 = cb + 64 * wc + ln;

  if (EPI == 2) {
    float* C = (float*)Cp + (size_t)blockIdx.z * sC;
#pragma unroll
    for (int mi = 0; mi < 4; ++mi) {
#pragma unroll
      for (int r = 0; r < 4; ++r) {
        const int R = row0 + 16 * mi + r;
        const float sr = s[R], tr = t[R];
#pragma unroll
        for (int ni = 0; ni < 4; ++ni) {
          float v = fmaf(acc[mi][ni][r], sr, tr);
          C[(size_t)R * ldc + (col0 + 16 * ni)] = v > 0.f ? v : 0.f;
        }
      }
    }
  } else {
    __hip_bfloat16* C = (__hip_bfloat16*)Cp + (size_t)blockIdx.z * sC;
    float sc[4], tc[4];
    if (EPI == 1) {
#pragma unroll
      for (int ni = 0; ni < 4; ++ni) { sc[ni] = s[col0 + 16 * ni]; tc[ni] = t[col0 + 16 * ni]; }
    }
#pragma unroll
    for (int mi = 0; mi < 4; ++mi) {
#pragma unroll
      for (int ni = 0; ni < 4; ++ni) {
#pragma unroll
        for (int r = 0; r < 4; ++r) {
          float v = acc[mi][ni][r];
          if (EPI == 1) { v = fmaf(v, sc[ni], tc[ni]); v = v > 0.f ? v : 0.f; }
          C[(size_t)(row0 + 16 * mi + r) * ldc + (col0 + 16 * ni)] = __float2bfloat16(v);
        }
      }
    }
  }
}

// ---------------- flash attention v2 ----------------
// Q,K: (B,4096,256) bf16; V: (B,256,4096) bf16; O: (B,4096,256) bf16
// 512 blocks (2/CU): batch = bid&7 (XCD-pinned), 64 q-rows/block, 4 waves.
// KVBLK=64. K/V staged via global_load_lds with pre-swizzled global source
// (XOR swizzle byte^=(row&7)<<4). Counted-vmcnt 3-barrier pipeline.
__global__ __launch_bounds__(256, 2) void flash_k(
    const __hip_bfloat16* __restrict__ Q,
    const __hip_bfloat16* __restrict__ Kt,
    const __hip_bfloat16* __restrict__ V,
    __hip_bfloat16* __restrict__ O) {
  __shared__ short Ks[64 * 256];   // 32 KB, swizzled
  __shared__ short Vs[256 * 64];   // 32 KB, swizzled
  __shared__ short Ps[4][16 * 64]; // 8 KB, per-wave, swizzled

  const int tid = threadIdx.x;
  const int w = tid >> 6, l = tid & 63, g = l >> 4, ln = l & 15;
  const int bid = blockIdx.x;
  const int batch = bid & 7;
  const int qb = (bid >> 3) << 6;
  const size_t bo = (size_t)batch * (4096 * 256);
  const float CE = 0.09016844005556021f;  // log2(e)/sqrt(256)

  // Q fragments (B-operand): lane ln = q-row (16w+ln), k = 32kk+8g+j
  bf16x8 qf[8];
  {
    const __hip_bfloat16* qp = Q + bo + (size_t)(qb + 16 * w + ln) * 256 + 8 * g;
#pragma unroll
    for (int kk = 0; kk < 8; ++kk) qf[kk] = *(const bf16x8*)(qp + 32 * kk);
  }

  f32x4 acc[16];
#pragma unroll
  for (int ci = 0; ci < 16; ++ci) acc[ci] = (f32x4){0.f, 0.f, 0.f, 0.f};
  float m_run = -1e30f, l_run = 0.f;

  // staging lane constants (pre-swizzled global chunk indices)
  const int kRow = 16 * w + (l >> 5);           // K row base (j adds 2j)
  const int kChunk = (l & 31) ^ (l >> 5);       // K chunk base
  const int vRow = 64 * w + (l >> 3);           // V cv row base (j adds 8j)
  const int vChunk = (l & 7) ^ ((l >> 3) & 7);  // V chunk (j-invariant)

  const short* Kb = (const short*)(Kt + bo);
  const short* Vb = (const short*)(V + bo);

  auto stageK = [&](int m0) {
#pragma unroll
    for (int j = 0; j < 8; ++j) {
      const short* gp = Kb + (size_t)(m0 + kRow + 2 * j) * 256 + 8 * (kChunk ^ ((2 * j) & 7));
      gload16(gp, Ks + w * 4096 + j * 512);
    }
  };
  auto stageV = [&](int m0) {
#pragma unroll
    for (int j = 0; j < 8; ++j) {
      const short* gp = Vb + (size_t)(vRow + 8 * j) * 4096 + m0 + 8 * vChunk;
      gload16(gp, Vs + w * 4096 + j * 512);
    }
  };

  stageK(0);
  stageV(0);
  __builtin_amdgcn_sched_barrier(0);

  for (int t = 0; t < 64; ++t) {
    // ---- barrier 1: K(t) landed (V(t) may still fly) ----
    asm volatile("s_waitcnt vmcnt(8)" ::: "memory");
    __builtin_amdgcn_sched_barrier(0);
    __builtin_amdgcn_s_barrier();
    __builtin_amdgcn_sched_barrier(0);

    // QK^T: S^T(64 keys x 16 q) — lane ln = q-row, keys 16mi+4g+r
    f32x4 sf[4];
#pragma unroll
    for (int mi = 0; mi < 4; ++mi) sf[mi] = (f32x4){0.f, 0.f, 0.f, 0.f};
    __builtin_amdgcn_s_setprio(1);
#pragma unroll
    for (int kk = 0; kk < 8; ++kk) {
#pragma unroll
      for (int mi = 0; mi < 4; ++mi) {
        const int idx = (((16 * mi + ln) * 256) + 32 * kk + 8 * g) ^ ((ln & 7) << 3);
        bf16x8 a = *(const bf16x8*)&Ks[idx];
        sf[mi] = MFMA16(a, qf[kk], sf[mi]);
      }
    }
    __builtin_amdgcn_s_setprio(0);

    // online softmax (per q-row = ln)
    float sv[16];
#pragma unroll
    for (int mi = 0; mi < 4; ++mi)
#pragma unroll
      for (int r = 0; r < 4; ++r) sv[4 * mi + r] = sf[mi][r];
    float mmax = sv[0];
#pragma unroll
    for (int j = 1; j < 16; ++j) mmax = fmaxf(mmax, sv[j]);
    mmax = fmaxf(mmax, __shfl_xor(mmax, 16));
    mmax = fmaxf(mmax, __shfl_xor(mmax, 32));

    if (!__all((mmax - m_run) * CE <= 8.0f)) {  // defer-max (T13)
      float m_new = fmaxf(m_run, mmax);
      float alpha = exp2f((m_run - m_new) * CE);
      l_run *= alpha;
#pragma unroll
      for (int r = 0; r < 4; ++r) {
        float ar = __shfl(alpha, 4 * g + r);  // acc rows are q=4g+r, alpha is per q=ln
#pragma unroll
        for (int ci = 0; ci < 16; ++ci) acc[ci][r] *= ar;
      }
      m_run = m_new;
    }
    float p[16], psum = 0.f;
#pragma unroll
    for (int j = 0; j < 16; ++j) {
      p[j] = exp2f((sv[j] - m_run) * CE);
      psum += p[j];
    }
    psum += __shfl_xor(psum, 16);
    psum += __shfl_xor(psum, 32);
    l_run += psum;

    // pack P into per-wave LDS (swizzled): Ps[q=ln][key]
#pragma unroll
    for (int mi = 0; mi < 4; ++mi) {
      uint2 pk;
      pk.x = (unsigned int)f2bf(p[4 * mi + 0]) | ((unsigned int)f2bf(p[4 * mi + 1]) << 16);
      pk.y = (unsigned int)f2bf(p[4 * mi + 2]) | ((unsigned int)f2bf(p[4 * mi + 3]) << 16);
      const int idx = (ln * 64 + 16 * mi + 4 * g) ^ ((ln & 7) << 3);
      *(uint2*)&Ps[w][idx] = pk;
    }

    // ---- barrier 2: V(t) landed + all waves done reading Ks(t) ----
    asm volatile("s_waitcnt vmcnt(0)" ::: "memory");
    __builtin_amdgcn_sched_barrier(0);
    __builtin_amdgcn_s_barrier();
    __builtin_amdgcn_sched_barrier(0);

    if (t < 63) stageK(64 * (t + 1));  // flies under PV
    __builtin_amdgcn_sched_barrier(0);

    // PV: ctx[q][cv] += P . V^T
    __builtin_amdgcn_s_setprio(1);
#pragma unroll
    for (int kk2 = 0; kk2 < 2; ++kk2) {
      const int pidx = (ln * 64 + 32 * kk2 + 8 * g) ^ ((ln & 7) << 3);
      bf16x8 pa = *(const bf16x8*)&Ps[w][pidx];
#pragma unroll
      for (int ci = 0; ci < 16; ++ci) {
        const int vidx = ((16 * ci + ln) * 64 + 32 * kk2 + 8 * g) ^ ((ln & 7) << 3);
        bf16x8 vfr = *(const bf16x8*)&Vs[vidx];
        acc[ci] = MFMA16(pa, vfr, acc[ci]);
      }
    }
    __builtin_amdgcn_s_setprio(0);

    // ---- barrier 3: all waves done reading Vs(t) ----
    __builtin_amdgcn_s_barrier();
    __builtin_amdgcn_sched_barrier(0);
    if (t < 63) stageV(64 * (t + 1));  // flies until next-iter vmcnt(0)
    __builtin_amdgcn_sched_barrier(0);
  }

  // epilogue: redistribute row-sums (l_run per q=ln -> rows q=4g+r), store
  float linv[4];
#pragma unroll
  for (int r = 0; r < 4; ++r) linv[r] = 1.0f / __shfl(l_run, 4 * g + r);

  __hip_bfloat16* Ob = O + bo;
#pragma unroll
  for (int ci = 0; ci < 16; ++ci) {
#pragma unroll
    for (int r = 0; r < 4; ++r) {
      float val = acc[ci][r] * linv[r];
      Ob[(size_t)(qb + 16 * w + 4 * g + r) * 256 + 16 * ci + ln] = __float2bfloat16(val);
    }
  }
}

// ---------------- host launcher ----------------

extern "C" void kernel_launch(void* const* d_in, const int* in_sizes, int n_in,
                              void* d_out, int out_size, void* d_ws, size_t ws_size,
                              hipStream_t stream) {
  const float* x   = (const float*)d_in[0];
  const float* kW1 = (const float*)d_in[1];
  const float* kG1 = (const float*)d_in[2];
  const float* kB1 = (const float*)d_in[3];
  const float* kM1 = (const float*)d_in[4];
  const float* kV1 = (const float*)d_in[5];
  const float* kW2 = (const float*)d_in[6];
  const float* kG2 = (const float*)d_in[7];
  const float* kB2 = (const float*)d_in[8];
  const float* kM2 = (const float*)d_in[9];
  const float* kV2 = (const float*)d_in[10];
  const float* qW1 = (const float*)d_in[11];
  const float* qG1 = (const float*)d_in[12];
  const float* qB1 = (const float*)d_in[13];
  const float* qM1 = (const float*)d_in[14];
  const float* qV1 = (const float*)d_in[15];
  const float* qW2 = (const float*)d_in[16];
  const float* qG2 = (const float*)d_in[17];
  const float* qB2 = (const float*)d_in[18];
  const float* qM2 = (const float*)d_in[19];
  const float* qV2 = (const float*)d_in[20];
  const float* vW  = (const float*)d_in[21];
  const float* wW  = (const float*)d_in[22];
  const float* wG  = (const float*)d_in[23];
  const float* wB  = (const float*)d_in[24];
  const float* wM  = (const float*)d_in[25];
  const float* wV  = (const float*)d_in[26];

  char* ws = (char*)d_ws;
  __hip_bfloat16* bQW1 = (__hip_bfloat16*)(ws + 0);
  __hip_bfloat16* bKW1 = (__hip_bfloat16*)(ws + 262144);
  __hip_bfloat16* bQW2 = (__hip_bfloat16*)(ws + 524288);
  __hip_bfloat16* bKW2 = (__hip_bfloat16*)(ws + 655360);
  __hip_bfloat16* bVW  = (__hip_bfloat16*)(ws + 786432);
  __hip_bfloat16* bWW  = (__hip_bfloat16*)(ws + 1048576);
  float* bnBase = (float*)(ws + 1310720);
  float* sQ1 = bnBase + 0;
  float* tQ1 = bnBase + 256;
  float* sQ2 = bnBase + 512;
  float* tQ2 = bnBase + 768;
  float* sK1 = bnBase + 1024;
  float* tK1 = bnBase + 1280;
  float* sK2 = bnBase + 1536;
  float* tK2 = bnBase + 1792;
  float* sWo = bnBase + 2048;
  float* tWo = bnBase + 2560;
  __hip_bfloat16* xT   = (__hip_bfloat16*)(ws + 2097152);    // 32 MB
  __hip_bfloat16* bufA = (__hip_bfloat16*)(ws + 35651584);   // 16 MB (q1 / k1 / ctx)
  __hip_bfloat16* q2b  = (__hip_bfloat16*)(ws + 52428800);   // 16 MB
  __hip_bfloat16* k2b  = (__hip_bfloat16*)(ws + 69206016);   // 16 MB
  __hip_bfloat16* vB   = (__hip_bfloat16*)(ws + 85983232);   // 16 MB

  conv_w_k<<<2560, 256, 0, stream>>>(qW1, kW1, qW2, kW2, vW, wW, bQW1);
  bn_all_k<<<6, 256, 0, stream>>>(qG1, qB1, qM1, qV1, qG2, qB2, qM2, qV2,
                                  kG1, kB1, kM1, kV1, kG2, kB2, kM2, kV2,
                                  wG, wB, wM, wV, bnBase);

  transpose_k<<<dim3(64, 8, 8), dim3(64, 4), 0, stream>>>(x, xT);

  // q1 = CBR(xT . qW1^T)
  gemm_nt_k<1><<<dim3(32, 2, 8), 256, 0, stream>>>(xT, 2097152L, bQW1, 0L, bufA, 1048576L,
                                                   512, 512, 256, 512, sQ1, tQ1);
  // q2 = CBR(q1 . qW2^T)
  gemm_nt_k<1><<<dim3(32, 2, 8), 256, 0, stream>>>(bufA, 1048576L, bQW2, 0L, q2b, 1048576L,
                                                   256, 256, 256, 256, sQ2, tQ2);
  // k1
  gemm_nt_k<1><<<dim3(32, 2, 8), 256, 0, stream>>>(xT, 2097152L, bKW1, 0L, bufA, 1048576L,
                                                   512, 512, 256, 512, sK1, tK1);
  // k2
  gemm_nt_k<1><<<dim3(32, 2, 8), 256, 0, stream>>>(bufA, 1048576L, bKW2, 0L, k2b, 1048576L,
                                                   256, 256, 256, 256, sK2, tK2);
  // v = vW . x -> (256 x 4096 per batch)
  gemm_nt_k<0><<<dim3(2, 32, 8), 256, 0, stream>>>(bVW, 0L, xT, 2097152L, vB, 1048576L,
                                                   512, 512, 4096, 512, nullptr, nullptr);
  // flash attention: ctx -> bufA
  flash_k<<<512, 256, 0, stream>>>(q2b, k2b, vB, bufA);
  // out = CBR_row(wW . ctx^T) -> d_out (fp32)
  gemm_nt_k<2><<<dim3(4, 32, 8), 256, 0, stream>>>(bWW, 0L, bufA, 1048576L, d_out, 2097152L,
                                                   256, 256, 4096, 256, sWo, tWo);
}

// Round 4
// 296.735 us; speedup vs baseline: 1.3603x; 1.0024x over previous
//
#include <hip/hip_runtime.h>
#include <hip/hip_bf16.h>

typedef __attribute__((ext_vector_type(8))) short bf16x8;
typedef __attribute__((ext_vector_type(4))) float f32x4;

#define MFMA16(a, b, c) __builtin_amdgcn_mfma_f32_16x16x32_bf16(a, b, c, 0, 0, 0)

static __device__ __forceinline__ unsigned short f2bf(float f) {
  union { __hip_bfloat16 h; unsigned short u; } cv;
  cv.h = __float2bfloat16(f);
  return cv.u;
}

static __device__ __forceinline__ void gload16(const void* gptr, void* lptr) {
  __builtin_amdgcn_global_load_lds(
      (const __attribute__((address_space(1))) void*)gptr,
      (__attribute__((address_space(3))) void*)lptr, 16, 0, 0);
}

// ---------------- fused prep kernels ----------------

__global__ void conv_w_k(const float* __restrict__ qW1, const float* __restrict__ kW1,
                         const float* __restrict__ qW2, const float* __restrict__ kW2,
                         const float* __restrict__ vW, const float* __restrict__ wW,
                         __hip_bfloat16* __restrict__ dst) {
  int i = blockIdx.x * 256 + threadIdx.x;  // 0..655359
  const float* src; int off;
  if (i < 131072)      { src = qW1; off = i; }
  else if (i < 262144) { src = kW1; off = i - 131072; }
  else if (i < 327680) { src = qW2; off = i - 262144; }
  else if (i < 393216) { src = kW2; off = i - 327680; }
  else if (i < 524288) { src = vW;  off = i - 393216; }
  else                 { src = wW;  off = i - 524288; }
  dst[i] = __float2bfloat16(src[off]);
}

__global__ void bn_all_k(const float* __restrict__ qG1, const float* __restrict__ qB1, const float* __restrict__ qM1, const float* __restrict__ qV1,
                         const float* __restrict__ qG2, const float* __restrict__ qB2, const float* __restrict__ qM2, const float* __restrict__ qV2,
                         const float* __restrict__ kG1, const float* __restrict__ kB1, const float* __restrict__ kM1, const float* __restrict__ kV1,
                         const float* __restrict__ kG2, const float* __restrict__ kB2, const float* __restrict__ kM2, const float* __restrict__ kV2,
                         const float* __restrict__ wG, const float* __restrict__ wB, const float* __restrict__ wM, const float* __restrict__ wV,
                         float* __restrict__ base) {
  int bidx = blockIdx.x, tid = threadIdx.x;
  const float *g, *b, *m, *v; float *s, *t; int i;
  if (bidx == 0)      { g = qG1; b = qB1; m = qM1; v = qV1; s = base;        t = base + 256;  i = tid; }
  else if (bidx == 1) { g = qG2; b = qB2; m = qM2; v = qV2; s = base + 512;  t = base + 768;  i = tid; }
  else if (bidx == 2) { g = kG1; b = kB1; m = kM1; v = kV1; s = base + 1024; t = base + 1280; i = tid; }
  else if (bidx == 3) { g = kG2; b = kB2; m = kM2; v = kV2; s = base + 1536; t = base + 1792; i = tid; }
  else                { g = wG;  b = wB;  m = wM;  v = wV;  s = base + 2048; t = base + 2560; i = (bidx - 4) * 256 + tid; }
  float sv = g[i] * rsqrtf(v[i] + 1e-5f);
  s[i] = sv;
  t[i] = b[i] - m[i] * sv;
}

// x (B,512,4096) fp32 -> xT (B,4096,512) bf16
__global__ __launch_bounds__(256) void transpose_k(const float* __restrict__ x,
                                                   __hip_bfloat16* __restrict__ xT) {
  __shared__ float tile[64][65];
  const int n0 = blockIdx.x * 64, c0 = blockIdx.y * 64, b = blockIdx.z;
  const int tx = threadIdx.x, ty = threadIdx.y;
  const float* xp = x + ((size_t)(b * 512 + c0) * 4096) + n0;
#pragma unroll
  for (int i = 0; i < 16; ++i) {
    int c = ty + 4 * i;
    tile[c][tx] = xp[(size_t)c * 4096 + tx];
  }
  __syncthreads();
  __hip_bfloat16* op = xT + ((size_t)(b * 4096 + n0) * 512) + c0;
#pragma unroll
  for (int i = 0; i < 16; ++i) {
    int nl = ty + 4 * i;
    op[(size_t)nl * 512 + tx] = __float2bfloat16(tile[tx][nl]);
  }
}

// ---------------- NT GEMM: C(MxN) = A(MxK) . B(NxK)^T ----------------
template <int EPI>
__global__ __launch_bounds__(256) void gemm_nt_k(
    const __hip_bfloat16* __restrict__ A, long sA,
    const __hip_bfloat16* __restrict__ B, long sB,
    void* __restrict__ Cp, long sC,
    int lda, int ldb, int ldc, int K,
    const float* __restrict__ s, const float* __restrict__ t) {
  __shared__ short As[128][72];
  __shared__ short Bs[128][72];
  const int tid = threadIdx.x;
  const int w = tid >> 6, l = tid & 63, g = l >> 4, ln = l & 15;
  const int wr = w >> 1, wc = w & 1;
  const int rb = blockIdx.x * 128, cb = blockIdx.y * 128;
  const __hip_bfloat16* Ab = A + (size_t)blockIdx.z * sA;
  const __hip_bfloat16* Bb = B + (size_t)blockIdx.z * sB;

  f32x4 acc[4][4];
#pragma unroll
  for (int i = 0; i < 4; ++i)
#pragma unroll
    for (int j = 0; j < 4; ++j) acc[i][j] = (f32x4){0.f, 0.f, 0.f, 0.f};

  const int r0 = tid >> 3;
  const int c8 = (tid & 7) * 8;

  for (int k0 = 0; k0 < K; k0 += 64) {
#pragma unroll
    for (int i = 0; i < 4; ++i) {
      const int r = r0 + 32 * i;
      *(uint4*)&As[r][c8] = *(const uint4*)(Ab + (size_t)(rb + r) * lda + (k0 + c8));
      *(uint4*)&Bs[r][c8] = *(const uint4*)(Bb + (size_t)(cb + r) * ldb + (k0 + c8));
    }
    __syncthreads();
#pragma unroll
    for (int kk = 0; kk < 2; ++kk) {
      bf16x8 av[4], bv[4];
#pragma unroll
      for (int i = 0; i < 4; ++i) av[i] = *(const bf16x8*)&As[64 * wr + 16 * i + ln][32 * kk + 8 * g];
#pragma unroll
      for (int i = 0; i < 4; ++i) bv[i] = *(const bf16x8*)&Bs[64 * wc + 16 * i + ln][32 * kk + 8 * g];
#pragma unroll
      for (int mi = 0; mi < 4; ++mi)
#pragma unroll
        for (int ni = 0; ni < 4; ++ni)
          acc[mi][ni] = MFMA16(av[mi], bv[ni], acc[mi][ni]);
    }
    __syncthreads();
  }

  const int row0 = rb + 64 * wr + 4 * g;
  const int col0 = cb + 64 * wc + ln;

  if (EPI == 2) {
    float* C = (float*)Cp + (size_t)blockIdx.z * sC;
#pragma unroll
    for (int mi = 0; mi < 4; ++mi) {
#pragma unroll
      for (int r = 0; r < 4; ++r) {
        const int R = row0 + 16 * mi + r;
        const float sr = s[R], tr = t[R];
#pragma unroll
        for (int ni = 0; ni < 4; ++ni) {
          float v = fmaf(acc[mi][ni][r], sr, tr);
          C[(size_t)R * ldc + (col0 + 16 * ni)] = v > 0.f ? v : 0.f;
        }
      }
    }
  } else {
    __hip_bfloat16* C = (__hip_bfloat16*)Cp + (size_t)blockIdx.z * sC;
    float sc[4], tc[4];
    if (EPI == 1) {
#pragma unroll
      for (int ni = 0; ni < 4; ++ni) { sc[ni] = s[col0 + 16 * ni]; tc[ni] = t[col0 + 16 * ni]; }
    }
#pragma unroll
    for (int mi = 0; mi < 4; ++mi) {
#pragma unroll
      for (int ni = 0; ni < 4; ++ni) {
#pragma unroll
        for (int r = 0; r < 4; ++r) {
          float v = acc[mi][ni][r];
          if (EPI == 1) { v = fmaf(v, sc[ni], tc[ni]); v = v > 0.f ? v : 0.f; }
          C[(size_t)(row0 + 16 * mi + r) * ldc + (col0 + 16 * ni)] = __float2bfloat16(v);
        }
      }
    }
  }
}

// ---------------- flash attention v3b (hoisted LDS addressing, P-write XOR fix) ----------------
// Q,K: (B,4096,256) bf16; V: (B,256,4096) bf16; O: (B,4096,256) bf16
// 512 blocks (2/CU): batch = bid&7 (XCD-pinned), 64 q-rows/block, 4 waves.
// KVBLK=64, XOR swizzle (byte bits 4-6), counted-vmcnt 3-barrier pipeline.
__global__ __launch_bounds__(256, 2) void flash_k(
    const __hip_bfloat16* __restrict__ Q,
    const __hip_bfloat16* __restrict__ Kt,
    const __hip_bfloat16* __restrict__ V,
    __hip_bfloat16* __restrict__ O) {
  __shared__ short Ks[64 * 256];  // 32 KB, swizzled: LDS[r][chunk c]=glob[r][c^(r&7)]
  __shared__ short Vs[256 * 64];  // 32 KB, swizzled
  __shared__ char Ps[4][2048];    // 8 KB per-wave P, swizzled

  const int tid = threadIdx.x;
  const int w = tid >> 6, l = tid & 63, g = l >> 4, ln = l & 15;
  const int bid = blockIdx.x;
  const int batch = bid & 7;
  const int qb = (bid >> 3) << 6;
  const size_t bo = (size_t)batch * (4096 * 256);
  const float CE = 0.09016844005556021f;  // log2(e)/sqrt(256)

  // ---- pre-loop hoisted LDS addressing ----
  // byte addr = row*stride + [col(bits4-5) ^ (ln&3)<<4] + [(colbit6) ^ ((ln>>2)&1)<<6] + higher
  const int swz45 = (16 * g) ^ ((ln & 3) << 4);  // bits 4-5
  const int s6 = ((ln >> 2) & 1) << 6;           // bit 6 of swizzle
  const char* Ks0 = (const char*)Ks + (ln * 512 + swz45 + s6);
  const char* Ks1 = Ks0 + ((((ln >> 2) & 1) ? -64 : 64));  // bit6 ^= 1
  const char* Vs0 = (const char*)Vs + (ln * 128 + swz45 + s6);
  const char* Vs1 = Vs0 + ((((ln >> 2) & 1) ? -64 : 64));
  const char* Pr0 = Ps[w] + (ln * 128 + swz45 + s6);
  const char* Pr1 = Pr0 + ((((ln >> 2) & 1) ? -64 : 64));
  // P write offset (mi=0 base); addr(mi) = pwOff ^ (mi<<5)  [XOR, not add!]
  const int pwOff = ln * 128 + 8 * (g & 1) + (((g >> 1) ^ (ln & 1)) << 4) +
                    (((ln >> 1) & 1) << 5) + s6;

  // Q fragments (B-operand): lane ln = q-row (16w+ln), k = 32kk+8g+j
  bf16x8 qf[8];
  {
    const __hip_bfloat16* qp = Q + bo + (size_t)(qb + 16 * w + ln) * 256 + 8 * g;
#pragma unroll
    for (int kk = 0; kk < 8; ++kk) qf[kk] = *(const bf16x8*)(qp + 32 * kk);
  }

  f32x4 acc[16];
#pragma unroll
  for (int ci = 0; ci < 16; ++ci) acc[ci] = (f32x4){0.f, 0.f, 0.f, 0.f};
  float m_run = -1e30f, l_run = 0.f;

  // staging lane constants (pre-swizzled global chunk indices)
  const int kRow = 16 * w + (l >> 5);
  const int kChunk = (l & 31) ^ (l >> 5);
  const int vRow = 64 * w + (l >> 3);
  const int vChunk = (l & 7) ^ ((l >> 3) & 7);

  const short* Kb = (const short*)(Kt + bo);
  const short* Vb = (const short*)(V + bo);

  auto stageK = [&](int m0) {
#pragma unroll
    for (int j = 0; j < 8; ++j) {
      const short* gp = Kb + (size_t)(m0 + kRow + 2 * j) * 256 + 8 * (kChunk ^ ((2 * j) & 7));
      gload16(gp, Ks + w * 4096 + j * 512);
    }
  };
  auto stageV = [&](int m0) {
#pragma unroll
    for (int j = 0; j < 8; ++j) {
      const short* gp = Vb + (size_t)(vRow + 8 * j) * 4096 + m0 + 8 * vChunk;
      gload16(gp, Vs + w * 4096 + j * 512);
    }
  };

  stageK(0);
  stageV(0);
  __builtin_amdgcn_sched_barrier(0);

  for (int t = 0; t < 64; ++t) {
    // ---- barrier 1: K(t) landed (V(t) may still fly) ----
    asm volatile("s_waitcnt vmcnt(8)" ::: "memory");
    __builtin_amdgcn_sched_barrier(0);
    __builtin_amdgcn_s_barrier();
    __builtin_amdgcn_sched_barrier(0);

    // QK^T: lane ln = q-row, keys 16mi+4g+r
    f32x4 sf[4];
#pragma unroll
    for (int mi = 0; mi < 4; ++mi) sf[mi] = (f32x4){0.f, 0.f, 0.f, 0.f};
    __builtin_amdgcn_s_setprio(1);
#pragma unroll
    for (int kk = 0; kk < 8; ++kk) {
      const char* kp = ((kk & 1) ? Ks1 : Ks0) + 128 * (kk >> 1);
#pragma unroll
      for (int mi = 0; mi < 4; ++mi) {
        bf16x8 a = *(const bf16x8*)(kp + 8192 * mi);
        sf[mi] = MFMA16(a, qf[kk], sf[mi]);
      }
    }
    __builtin_amdgcn_s_setprio(0);

    // online softmax (per q-row = ln)
    float sv[16];
#pragma unroll
    for (int mi = 0; mi < 4; ++mi)
#pragma unroll
      for (int r = 0; r < 4; ++r) sv[4 * mi + r] = sf[mi][r];
    float a0 = fmaxf(fmaxf(sv[0], sv[1]), sv[2]);
    float a1 = fmaxf(fmaxf(sv[3], sv[4]), sv[5]);
    float a2 = fmaxf(fmaxf(sv[6], sv[7]), sv[8]);
    float a3 = fmaxf(fmaxf(sv[9], sv[10]), sv[11]);
    float a4 = fmaxf(fmaxf(sv[12], sv[13]), sv[14]);
    float mmax = fmaxf(fmaxf(fmaxf(fmaxf(a0, a1), a2), fmaxf(a3, a4)), sv[15]);
    mmax = fmaxf(mmax, __shfl_xor(mmax, 16));
    mmax = fmaxf(mmax, __shfl_xor(mmax, 32));

    if (!__all((mmax - m_run) * CE <= 8.0f)) {  // defer-max (T13)
      float m_new = fmaxf(m_run, mmax);
      float alpha = exp2f((m_run - m_new) * CE);
      l_run *= alpha;
#pragma unroll
      for (int r = 0; r < 4; ++r) {
        float ar = __shfl(alpha, 4 * g + r);
#pragma unroll
        for (int ci = 0; ci < 16; ++ci) acc[ci][r] *= ar;
      }
      m_run = m_new;
    }
    float p[16], psum = 0.f;
#pragma unroll
    for (int j = 0; j < 16; ++j) {
      p[j] = exp2f((sv[j] - m_run) * CE);
      psum += p[j];
    }
    psum += __shfl_xor(psum, 16);
    psum += __shfl_xor(psum, 32);
    l_run += psum;

    // pack P (bf16) into per-wave LDS, swizzled; addr(mi) = pwOff ^ (mi<<5)
    {
      uint2 pk0, pk1, pk2, pk3;
      pk0.x = (unsigned int)f2bf(p[0])  | ((unsigned int)f2bf(p[1])  << 16);
      pk0.y = (unsigned int)f2bf(p[2])  | ((unsigned int)f2bf(p[3])  << 16);
      pk1.x = (unsigned int)f2bf(p[4])  | ((unsigned int)f2bf(p[5])  << 16);
      pk1.y = (unsigned int)f2bf(p[6])  | ((unsigned int)f2bf(p[7])  << 16);
      pk2.x = (unsigned int)f2bf(p[8])  | ((unsigned int)f2bf(p[9])  << 16);
      pk2.y = (unsigned int)f2bf(p[10]) | ((unsigned int)f2bf(p[11]) << 16);
      pk3.x = (unsigned int)f2bf(p[12]) | ((unsigned int)f2bf(p[13]) << 16);
      pk3.y = (unsigned int)f2bf(p[14]) | ((unsigned int)f2bf(p[15]) << 16);
      *(uint2*)(Ps[w] + (pwOff ^ 0))  = pk0;
      *(uint2*)(Ps[w] + (pwOff ^ 32)) = pk1;
      *(uint2*)(Ps[w] + (pwOff ^ 64)) = pk2;
      *(uint2*)(Ps[w] + (pwOff ^ 96)) = pk3;
    }

    // ---- barrier 2: V(t) landed + all waves done reading Ks(t) ----
    asm volatile("s_waitcnt vmcnt(0)" ::: "memory");
    __builtin_amdgcn_sched_barrier(0);
    __builtin_amdgcn_s_barrier();
    __builtin_amdgcn_sched_barrier(0);

    if (t < 63) stageK(64 * (t + 1));  // flies under PV
    __builtin_amdgcn_sched_barrier(0);

    // PV: ctx[q][cv] += P . V^T
    __builtin_amdgcn_s_setprio(1);
#pragma unroll
    for (int kk2 = 0; kk2 < 2; ++kk2) {
      bf16x8 pa = *(const bf16x8*)(kk2 ? Pr1 : Pr0);
#pragma unroll
      for (int ci = 0; ci < 16; ++ci) {
        bf16x8 vfr = *(const bf16x8*)((kk2 ? Vs1 : Vs0) + 2048 * ci);
        acc[ci] = MFMA16(pa, vfr, acc[ci]);
      }
    }
    __builtin_amdgcn_s_setprio(0);

    // ---- barrier 3: all waves done reading Vs(t) ----
    __builtin_amdgcn_s_barrier();
    __builtin_amdgcn_sched_barrier(0);
    if (t < 63) stageV(64 * (t + 1));  // flies until next-iter vmcnt(0)
    __builtin_amdgcn_sched_barrier(0);
  }

  // epilogue
  float linv[4];
#pragma unroll
  for (int r = 0; r < 4; ++r) linv[r] = 1.0f / __shfl(l_run, 4 * g + r);

  __hip_bfloat16* Ob = O + bo;
#pragma unroll
  for (int ci = 0; ci < 16; ++ci) {
#pragma unroll
    for (int r = 0; r < 4; ++r) {
      float val = acc[ci][r] * linv[r];
      Ob[(size_t)(qb + 16 * w + 4 * g + r) * 256 + 16 * ci + ln] = __float2bfloat16(val);
    }
  }
}

// ---------------- host launcher ----------------

extern "C" void kernel_launch(void* const* d_in, const int* in_sizes, int n_in,
                              void* d_out, int out_size, void* d_ws, size_t ws_size,
                              hipStream_t stream) {
  const float* x   = (const float*)d_in[0];
  const float* kW1 = (const float*)d_in[1];
  const float* kG1 = (const float*)d_in[2];
  const float* kB1 = (const float*)d_in[3];
  const float* kM1 = (const float*)d_in[4];
  const float* kV1 = (const float*)d_in[5];
  const float* kW2 = (const float*)d_in[6];
  const float* kG2 = (const float*)d_in[7];
  const float* kB2 = (const float*)d_in[8];
  const float* kM2 = (const float*)d_in[9];
  const float* kV2 = (const float*)d_in[10];
  const float* qW1 = (const float*)d_in[11];
  const float* qG1 = (const float*)d_in[12];
  const float* qB1 = (const float*)d_in[13];
  const float* qM1 = (const float*)d_in[14];
  const float* qV1 = (const float*)d_in[15];
  const float* qW2 = (const float*)d_in[16];
  const float* qG2 = (const float*)d_in[17];
  const float* qB2 = (const float*)d_in[18];
  const float* qM2 = (const float*)d_in[19];
  const float* qV2 = (const float*)d_in[20];
  const float* vW  = (const float*)d_in[21];
  const float* wW  = (const float*)d_in[22];
  const float* wG  = (const float*)d_in[23];
  const float* wB  = (const float*)d_in[24];
  const float* wM  = (const float*)d_in[25];
  const float* wV  = (const float*)d_in[26];

  char* ws = (char*)d_ws;
  __hip_bfloat16* bQW1 = (__hip_bfloat16*)(ws + 0);
  __hip_bfloat16* bKW1 = (__hip_bfloat16*)(ws + 262144);
  __hip_bfloat16* bQW2 = (__hip_bfloat16*)(ws + 524288);
  __hip_bfloat16* bKW2 = (__hip_bfloat16*)(ws + 655360);
  __hip_bfloat16* bVW  = (__hip_bfloat16*)(ws + 786432);
  __hip_bfloat16* bWW  = (__hip_bfloat16*)(ws + 1048576);
  float* bnBase = (float*)(ws + 1310720);
  float* sQ1 = bnBase + 0;
  float* tQ1 = bnBase + 256;
  float* sQ2 = bnBase + 512;
  float* tQ2 = bnBase + 768;
  float* sK1 = bnBase + 1024;
  float* tK1 = bnBase + 1280;
  float* sK2 = bnBase + 1536;
  float* tK2 = bnBase + 1792;
  float* sWo = bnBase + 2048;
  float* tWo = bnBase + 2560;
  __hip_bfloat16* xT   = (__hip_bfloat16*)(ws + 2097152);    // 32 MB
  __hip_bfloat16* bufA = (__hip_bfloat16*)(ws + 35651584);   // 16 MB (q1 / k1 / ctx)
  __hip_bfloat16* q2b  = (__hip_bfloat16*)(ws + 52428800);   // 16 MB
  __hip_bfloat16* k2b  = (__hip_bfloat16*)(ws + 69206016);   // 16 MB
  __hip_bfloat16* vB   = (__hip_bfloat16*)(ws + 85983232);   // 16 MB

  conv_w_k<<<2560, 256, 0, stream>>>(qW1, kW1, qW2, kW2, vW, wW, bQW1);
  bn_all_k<<<6, 256, 0, stream>>>(qG1, qB1, qM1, qV1, qG2, qB2, qM2, qV2,
                                  kG1, kB1, kM1, kV1, kG2, kB2, kM2, kV2,
                                  wG, wB, wM, wV, bnBase);

  transpose_k<<<dim3(64, 8, 8), dim3(64, 4), 0, stream>>>(x, xT);

  // q1 = CBR(xT . qW1^T)
  gemm_nt_k<1><<<dim3(32, 2, 8), 256, 0, stream>>>(xT, 2097152L, bQW1, 0L, bufA, 1048576L,
                                                   512, 512, 256, 512, sQ1, tQ1);
  // q2 = CBR(q1 . qW2^T)
  gemm_nt_k<1><<<dim3(32, 2, 8), 256, 0, stream>>>(bufA, 1048576L, bQW2, 0L, q2b, 1048576L,
                                                   256, 256, 256, 256, sQ2, tQ2);
  // k1
  gemm_nt_k<1><<<dim3(32, 2, 8), 256, 0, stream>>>(xT, 2097152L, bKW1, 0L, bufA, 1048576L,
                                                   512, 512, 256, 512, sK1, tK1);
  // k2
  gemm_nt_k<1><<<dim3(32, 2, 8), 256, 0, stream>>>(bufA, 1048576L, bKW2, 0L, k2b, 1048576L,
                                                   256, 256, 256, 256, sK2, tK2);
  // v = vW . x -> (256 x 4096 per batch)
  gemm_nt_k<0><<<dim3(2, 32, 8), 256, 0, stream>>>(bVW, 0L, xT, 2097152L, vB, 1048576L,
                                                   512, 512, 4096, 512, nullptr, nullptr);
  // flash attention: ctx -> bufA
  flash_k<<<512, 256, 0, stream>>>(q2b, k2b, vB, bufA);
  // out = CBR_row(wW . ctx^T) -> d_out (fp32)
  gemm_nt_k<2><<<dim3(4, 32, 8), 256, 0, stream>>>(bWW, 0L, bufA, 1048576L, d_out, 2097152L,
                                                   256, 256, 4096, 256, sWo, tWo);
}